// Round 2
// baseline (2280.891 us; speedup 1.0000x reference)
//
#include <hip/hip_runtime.h>
#include <hip/hip_bf16.h>
#include <math.h>

#define L_ 4096
#define C96 96
#define D192 192
#define N16 16
#define EPSF 1e-5f

__device__ __forceinline__ int swap64(int v) { return ((v & 63) << 6) | (v >> 6); }
__device__ __forceinline__ float silu_(float x) { return x / (1.f + __expf(-x)); }
__device__ __forceinline__ float softplus_(float x) { return (x > 20.f) ? x : log1pf(__expf(x)); }

// K1: depthwise 3x3 conv on x [B,C,H,W] -> hpre [B, L, C] (pixel-major BHWC)
__global__ __launch_bounds__(256) void k_dwconv1(const float* __restrict__ x,
                                                 const float* __restrict__ w,
                                                 const float* __restrict__ bias,
                                                 float* __restrict__ hpre) {
    int idx = blockIdx.x * 256 + threadIdx.x;       // over B*C*H*W
    int wi = idx & 63, hi = (idx >> 6) & 63, bc = idx >> 12;
    int c = bc % C96, b = bc / C96;
    const float* xp = x + (size_t)bc * L_;
    float acc = bias[c];
#pragma unroll
    for (int kh = 0; kh < 3; kh++) {
        int hh = hi + kh - 1;
        if (hh < 0 || hh >= 64) continue;
#pragma unroll
        for (int kw = 0; kw < 3; kw++) {
            int wp = wi + kw - 1;
            if (wp < 0 || wp >= 64) continue;
            acc += xp[hh * 64 + wp] * w[c * 9 + kh * 3 + kw];
        }
    }
    hpre[((size_t)b * L_ + hi * 64 + wi) * C96 + c] = acc;
}

// K2: LN over C (ln_w/ln_b) then in_proj GEMM: [64 pixels x 96] @ [96 x 64 j's]
// j<192 -> xi [B*L,192]; j>=192 -> z [B*L,192]
__global__ __launch_bounds__(256) void k_ln_inproj(const float* __restrict__ hpre,
                                                   const float* __restrict__ lnw,
                                                   const float* __restrict__ lnb,
                                                   const float* __restrict__ ipw,
                                                   float* __restrict__ xi,
                                                   float* __restrict__ z) {
    __shared__ float At[64][97];
    __shared__ float Bt[96][65];
    int m0 = blockIdx.x * 64;
    int j0 = blockIdx.y * 64;
    int tid = threadIdx.x;
    for (int q = tid; q < 64 * 96; q += 256) {
        int r = q / 96, ci = q % 96;
        At[r][ci] = hpre[(size_t)(m0 + r) * 96 + ci];
    }
    for (int q = tid; q < 96 * 64; q += 256) {
        int jj = q / 96, i = q % 96;
        Bt[i][jj] = ipw[(size_t)(j0 + jj) * 96 + i];
    }
    __syncthreads();
    // LayerNorm each row (4 threads per row, same wave)
    int row = tid >> 2, qq = tid & 3;
    float s = 0.f, s2 = 0.f;
    for (int ci = qq; ci < 96; ci += 4) { float v = At[row][ci]; s += v; s2 += v * v; }
    s += __shfl_xor(s, 1);  s += __shfl_xor(s, 2);
    s2 += __shfl_xor(s2, 1); s2 += __shfl_xor(s2, 2);
    float mean = s * (1.f / 96.f);
    float var = s2 * (1.f / 96.f) - mean * mean;
    float rstd = rsqrtf(var + EPSF);
    for (int ci = qq; ci < 96; ci += 4) {
        float v = At[row][ci];
        At[row][ci] = (v - mean) * rstd * lnw[ci] + lnb[ci];
    }
    __syncthreads();
    // 64x64 GEMM over K=96
    int tm = tid & 15, tn = tid >> 4;
    float acc[4][4];
#pragma unroll
    for (int r = 0; r < 4; r++)
#pragma unroll
        for (int cx = 0; cx < 4; cx++) acc[r][cx] = 0.f;
    for (int kk = 0; kk < 96; kk++) {
        float a0 = At[tm * 4 + 0][kk], a1 = At[tm * 4 + 1][kk];
        float a2 = At[tm * 4 + 2][kk], a3 = At[tm * 4 + 3][kk];
        float b0 = Bt[kk][tn * 4 + 0], b1 = Bt[kk][tn * 4 + 1];
        float b2 = Bt[kk][tn * 4 + 2], b3 = Bt[kk][tn * 4 + 3];
        acc[0][0] = fmaf(a0, b0, acc[0][0]); acc[0][1] = fmaf(a0, b1, acc[0][1]);
        acc[0][2] = fmaf(a0, b2, acc[0][2]); acc[0][3] = fmaf(a0, b3, acc[0][3]);
        acc[1][0] = fmaf(a1, b0, acc[1][0]); acc[1][1] = fmaf(a1, b1, acc[1][1]);
        acc[1][2] = fmaf(a1, b2, acc[1][2]); acc[1][3] = fmaf(a1, b3, acc[1][3]);
        acc[2][0] = fmaf(a2, b0, acc[2][0]); acc[2][1] = fmaf(a2, b1, acc[2][1]);
        acc[2][2] = fmaf(a2, b2, acc[2][2]); acc[2][3] = fmaf(a2, b3, acc[2][3]);
        acc[3][0] = fmaf(a3, b0, acc[3][0]); acc[3][1] = fmaf(a3, b1, acc[3][1]);
        acc[3][2] = fmaf(a3, b2, acc[3][2]); acc[3][3] = fmaf(a3, b3, acc[3][3]);
    }
#pragma unroll
    for (int r = 0; r < 4; r++) {
        int m = m0 + tm * 4 + r;
#pragma unroll
        for (int cx = 0; cx < 4; cx++) {
            int j = j0 + tn * 4 + cx;
            if (j < 192) xi[(size_t)m * 192 + j] = acc[r][cx];
            else         z[(size_t)m * 192 + (j - 192)] = acc[r][cx];
        }
    }
}

// K3: depthwise 3x3 conv on xi [B,L,D] (pixel-major) + bias + SiLU -> xc [B,L,D]
__global__ __launch_bounds__(256) void k_dwconv2(const float* __restrict__ xi,
                                                 const float* __restrict__ w,
                                                 const float* __restrict__ bias,
                                                 float* __restrict__ xc) {
    int idx = blockIdx.x * 256 + threadIdx.x;        // over B*L*D, d fastest
    int d = idx % D192;
    int rest = idx / D192;
    int l = rest & 4095, b = rest >> 12;
    int hi = l >> 6, wi = l & 63;
    float acc = bias[d];
#pragma unroll
    for (int kh = 0; kh < 3; kh++) {
        int hh = hi + kh - 1;
        if (hh < 0 || hh >= 64) continue;
#pragma unroll
        for (int kw = 0; kw < 3; kw++) {
            int wp = wi + kw - 1;
            if (wp < 0 || wp >= 64) continue;
            acc += xi[((size_t)(b << 12) + hh * 64 + wp) * D192 + d] * w[d * 9 + kh * 3 + kw];
        }
    }
    xc[(size_t)idx] = silu_(acc);
}

// K4: x_proj (dts/Bs/Cs) + dt_proj + softplus. One block = 64 pixels.
__global__ __launch_bounds__(256) void k_proj(const float* __restrict__ xc,
                                              const float* __restrict__ xpw,
                                              const float* __restrict__ dtw,
                                              const float* __restrict__ dtb,
                                              float* __restrict__ delta,
                                              float* __restrict__ Bsb,
                                              float* __restrict__ Csb) {
    __shared__ float xt[64][193];
    __shared__ float dts[4][64][6];
    int m0 = blockIdx.x * 64;
    int tid = threadIdx.x;
    for (int q = tid; q < 64 * 192; q += 256) {
        int p = q / 192, d = q % 192;
        xt[p][d] = xc[(size_t)(m0 + p) * 192 + d];
    }
    __syncthreads();
    // x_dbl: 4*38 outputs per pixel; wave-uniform (k,c) -> weight row broadcast
    for (int q = tid; q < 4 * 38 * 64; q += 256) {
        int p = q & 63, kc = q >> 6;
        int k = kc / 38, c = kc % 38;
        const float* wr = xpw + (size_t)(k * 38 + c) * 192;
        float s = 0.f;
#pragma unroll 8
        for (int d = 0; d < 192; d++) s = fmaf(xt[p][d], wr[d], s);
        int m = m0 + p, b = m >> 12, l = m & 4095;
        int lseq = (k == 0) ? l : (k == 1) ? swap64(l) : (k == 2) ? (4095 - l) : (4095 - swap64(l));
        int bk = (b << 2) | k;
        if (c < 6)       dts[k][p][c] = s;
        else if (c < 22) Bsb[((size_t)bk * L_ + lseq) * N16 + (c - 6)] = s;
        else             Csb[((size_t)bk * L_ + lseq) * N16 + (c - 22)] = s;
    }
    __syncthreads();
    // dt_proj + bias + softplus -> delta [bk][lseq][192]
    for (int q = tid; q < 4 * 64 * 192; q += 256) {
        int d = q % 192;
        int rest = q / 192;
        int p = rest & 63, k = rest >> 6;
        int m = m0 + p, b = m >> 12, l = m & 4095;
        int lseq = (k == 0) ? l : (k == 1) ? swap64(l) : (k == 2) ? (4095 - l) : (4095 - swap64(l));
        const float* wr = dtw + (size_t)(k * 192 + d) * 6;
        float s = dtb[k * 192 + d];
#pragma unroll
        for (int r = 0; r < 6; r++) s = fmaf(dts[k][p][r], wr[r], s);
        delta[((size_t)((b << 2) | k) * L_ + lseq) * D192 + d] = softplus_(s);
    }
}

// K5: selective scan. block = 16 d-channels x 16 n-lanes; grid = (B*K, D/16)
__global__ __launch_bounds__(256) void k_scan(const float* __restrict__ xc,
                                              const float* __restrict__ delta,
                                              const float* __restrict__ Bsb,
                                              const float* __restrict__ Csb,
                                              const float* __restrict__ Alogs,
                                              const float* __restrict__ Ds,
                                              float* __restrict__ outy) {
    int bk = blockIdx.x;
    int b = bk >> 2, k = bk & 3;
    int dbase = blockIdx.y * 16;
    int g = threadIdx.x >> 4, n = threadIdx.x & 15;
    int d = dbase + g;
    float a = -expf(Alogs[(size_t)(k * D192 + d) * N16 + n]);
    float Dv = Ds[k * D192 + d];
    const float* xcb = xc + (size_t)(b << 12) * D192;
    const float* dp = delta + (size_t)bk * L_ * D192;
    const float* Bp = Bsb + (size_t)bk * L_ * N16;
    const float* Cp = Csb + (size_t)bk * L_ * N16;
    float* Op = outy + (size_t)bk * L_ * D192;
    float h = 0.f;
#pragma unroll 4
    for (int l = 0; l < L_; l++) {
        int lsp;
        if (k == 0)      lsp = l;
        else if (k == 1) lsp = swap64(l);
        else if (k == 2) lsp = 4095 - l;
        else           { int mm = 4095 - l; lsp = swap64(mm); }
        float u = xcb[(size_t)lsp * D192 + d];
        float dl = dp[(size_t)l * D192 + d];
        float Bn = Bp[l * N16 + n];
        float Cn = Cp[l * N16 + n];
        float dA = __expf(dl * a);
        h = fmaf(h, dA, dl * u * Bn);
        float yp = h * Cn;
        yp += __shfl_xor(yp, 1);
        yp += __shfl_xor(yp, 2);
        yp += __shfl_xor(yp, 4);
        yp += __shfl_xor(yp, 8);
        if (n == 0) Op[(size_t)l * D192 + d] = fmaf(Dv, u, yp);
    }
}

// K6: combine 4 directions + LN(out_norm) + *silu(z) + out_proj + add hpre -> h2
// h2 stored BCHW-like: [(b*96+c)][L]
__global__ __launch_bounds__(256) void k_combine(const float* __restrict__ outy,
                                                 const float* __restrict__ onw,
                                                 const float* __restrict__ onb,
                                                 const float* __restrict__ z,
                                                 const float* __restrict__ opw,
                                                 const float* __restrict__ hpre,
                                                 float* __restrict__ h2) {
    __shared__ float yb[64][193];
    int m0 = blockIdx.x * 64;
    int tid = threadIdx.x;
    int b = m0 >> 12;
    const float* oy = outy + (size_t)(b << 2) * L_ * D192;
    for (int q = tid; q < 64 * 192; q += 256) {
        int d = q % 192, p = q / 192;
        int l = (m0 & 4095) + p;
        int l1 = swap64(l);
        float v = oy[((size_t)0 * L_ + l) * D192 + d]
                + oy[((size_t)2 * L_ + (4095 - l)) * D192 + d]
                + oy[((size_t)1 * L_ + l1) * D192 + d]
                + oy[((size_t)3 * L_ + (4095 - l1)) * D192 + d];
        yb[p][d] = v;
    }
    __syncthreads();
    int row = tid >> 2, qq = tid & 3;
    float s = 0.f, s2 = 0.f;
    for (int ci = qq; ci < 192; ci += 4) { float v = yb[row][ci]; s += v; s2 += v * v; }
    s += __shfl_xor(s, 1);  s += __shfl_xor(s, 2);
    s2 += __shfl_xor(s2, 1); s2 += __shfl_xor(s2, 2);
    float mean = s * (1.f / 192.f);
    float var = s2 * (1.f / 192.f) - mean * mean;
    float rstd = rsqrtf(var + EPSF);
    int m = m0 + row;
    for (int ci = qq; ci < 192; ci += 4) {
        float v = (yb[row][ci] - mean) * rstd * onw[ci] + onb[ci];
        float zz = z[(size_t)m * 192 + ci];
        yb[row][ci] = v * silu_(zz);
    }
    __syncthreads();
    for (int q = tid; q < 64 * 96; q += 256) {
        int p = q & 63, c = q >> 6;
        const float* wr = opw + (size_t)c * 192;
        float s3 = 0.f;
#pragma unroll 8
        for (int d = 0; d < 192; d++) s3 = fmaf(yb[p][d], wr[d], s3);
        int mm = m0 + p, bb = mm >> 12, l = mm & 4095;
        h2[((size_t)(bb * 96 + c)) * L_ + l] = hpre[(size_t)mm * 96 + c] + s3;
    }
}

// K7a: instance-norm stats over HW per (b,c)
__global__ __launch_bounds__(256) void k_instats(const float* __restrict__ h2,
                                                 float* __restrict__ stats) {
    int bc = blockIdx.x;
    int tid = threadIdx.x;
    const float* p = h2 + (size_t)bc * L_;
    float s = 0.f, s2 = 0.f;
    for (int i = tid; i < L_; i += 256) { float v = p[i]; s += v; s2 += v * v; }
#pragma unroll
    for (int off = 1; off < 64; off <<= 1) { s += __shfl_xor(s, off); s2 += __shfl_xor(s2, off); }
    __shared__ float w1[4], w2[4];
    int wv = tid >> 6;
    if ((tid & 63) == 0) { w1[wv] = s; w2[wv] = s2; }
    __syncthreads();
    if (tid == 0) {
        s = w1[0] + w1[1] + w1[2] + w1[3];
        s2 = w2[0] + w2[1] + w2[2] + w2[3];
        float mean = s * (1.f / L_);
        float var = s2 * (1.f / L_) - mean * mean;
        stats[bc * 2] = mean;
        stats[bc * 2 + 1] = rsqrtf(var + EPSF);
    }
}

// K7b: final: instance-norm apply + LeakyReLU + skip*scale -> f32 out [B,C,H,W]
__global__ __launch_bounds__(256) void k_final(const float* __restrict__ h2,
                                               const float* __restrict__ stats,
                                               const float* __restrict__ inw,
                                               const float* __restrict__ inb,
                                               const float* __restrict__ x,
                                               const float* __restrict__ scale,
                                               float* __restrict__ out) {
    int idx = blockIdx.x * 256 + threadIdx.x;
    int bc = idx >> 12;
    int c = bc % 96;
    float mean = stats[bc * 2], rstd = stats[bc * 2 + 1];
    float v = (h2[idx] - mean) * rstd * inw[c] + inb[c];
    v = (v >= 0.f) ? v : 0.01f * v;
    v = fmaf(x[idx], scale[0], v);
    out[idx] = v;
}

extern "C" void kernel_launch(void* const* d_in, const int* in_sizes, int n_in,
                              void* d_out, int out_size, void* d_ws, size_t ws_size,
                              hipStream_t stream) {
    const float* x         = (const float*)d_in[0];
    const float* conv_w    = (const float*)d_in[1];
    const float* conv_b    = (const float*)d_in[2];
    const float* inorm_w   = (const float*)d_in[3];
    const float* inorm_b   = (const float*)d_in[4];
    const float* scale     = (const float*)d_in[5];
    const float* ln_w      = (const float*)d_in[6];
    const float* ln_b      = (const float*)d_in[7];
    const float* in_proj_w = (const float*)d_in[8];
    const float* conv2_w   = (const float*)d_in[9];
    const float* conv2_b   = (const float*)d_in[10];
    const float* x_proj_w  = (const float*)d_in[11];
    const float* dt_proj_w = (const float*)d_in[12];
    const float* dt_proj_b = (const float*)d_in[13];
    const float* A_logs    = (const float*)d_in[14];
    const float* Ds        = (const float*)d_in[15];
    const float* out_nw    = (const float*)d_in[16];
    const float* out_nb    = (const float*)d_in[17];
    const float* out_pw    = (const float*)d_in[18];

    float* ws = (float*)d_ws;
    float* hpre  = ws;                    // 786432
    float* xi    = hpre + 786432;         // 1572864
    float* z     = xi + 1572864;          // 1572864
    float* xc    = z + 1572864;           // 1572864
    float* delta = xc + 1572864;          // 6291456
    float* Bsb   = delta + 6291456;       // 524288
    float* Csb   = Bsb + 524288;          // 524288
    float* outy  = Csb + 524288;          // 6291456
    float* h2    = outy + 6291456;        // 786432
    float* stats = h2 + 786432;           // 384

    k_dwconv1<<<3072, 256, 0, stream>>>(x, conv_w, conv_b, hpre);
    k_ln_inproj<<<dim3(128, 6), 256, 0, stream>>>(hpre, ln_w, ln_b, in_proj_w, xi, z);
    k_dwconv2<<<6144, 256, 0, stream>>>(xi, conv2_w, conv2_b, xc);
    k_proj<<<128, 256, 0, stream>>>(xc, x_proj_w, dt_proj_w, dt_proj_b, delta, Bsb, Csb);
    k_scan<<<dim3(8, 12), 256, 0, stream>>>(xc, delta, Bsb, Csb, A_logs, Ds, outy);
    k_combine<<<128, 256, 0, stream>>>(outy, out_nw, out_nb, z, out_pw, hpre, h2);
    k_instats<<<192, 256, 0, stream>>>(h2, stats);
    k_final<<<3072, 256, 0, stream>>>(h2, stats, inorm_w, inorm_b, x, scale,
                                      (float*)d_out);
}

// Round 3
// 546.542 us; speedup vs baseline: 4.1733x; 4.1733x over previous
//
#include <hip/hip_runtime.h>
#include <hip/hip_bf16.h>
#include <math.h>

#define L_ 4096
#define C96 96
#define D192 192
#define N16 16
#define EPSF 1e-5f
#define NSEG 64
#define SEGLEN 64

__device__ __forceinline__ int swap64(int v) { return ((v & 63) << 6) | (v >> 6); }
__device__ __forceinline__ float silu_(float x) { return x / (1.f + __expf(-x)); }
__device__ __forceinline__ float softplus_(float x) { return (x > 20.f) ? x : log1pf(__expf(x)); }
__device__ __forceinline__ int lperm(int k, int l) {
    return (k == 0) ? l : (k == 1) ? swap64(l) : (k == 2) ? (4095 - l) : swap64(4095 - l);
}

// K1: depthwise 3x3 conv on x [B,C,H,W] -> hpre [B, L, C] (pixel-major BHWC)
__global__ __launch_bounds__(256) void k_dwconv1(const float* __restrict__ x,
                                                 const float* __restrict__ w,
                                                 const float* __restrict__ bias,
                                                 float* __restrict__ hpre) {
    int idx = blockIdx.x * 256 + threadIdx.x;       // over B*C*H*W
    int wi = idx & 63, hi = (idx >> 6) & 63, bc = idx >> 12;
    int c = bc % C96, b = bc / C96;
    const float* xp = x + (size_t)bc * L_;
    float acc = bias[c];
#pragma unroll
    for (int kh = 0; kh < 3; kh++) {
        int hh = hi + kh - 1;
        if (hh < 0 || hh >= 64) continue;
#pragma unroll
        for (int kw = 0; kw < 3; kw++) {
            int wp = wi + kw - 1;
            if (wp < 0 || wp >= 64) continue;
            acc += xp[hh * 64 + wp] * w[c * 9 + kh * 3 + kw];
        }
    }
    hpre[((size_t)b * L_ + hi * 64 + wi) * C96 + c] = acc;
}

// K2: LN over C (ln_w/ln_b) then in_proj GEMM
__global__ __launch_bounds__(256) void k_ln_inproj(const float* __restrict__ hpre,
                                                   const float* __restrict__ lnw,
                                                   const float* __restrict__ lnb,
                                                   const float* __restrict__ ipw,
                                                   float* __restrict__ xi,
                                                   float* __restrict__ z) {
    __shared__ float At[64][97];
    __shared__ float Bt[96][65];
    int m0 = blockIdx.x * 64;
    int j0 = blockIdx.y * 64;
    int tid = threadIdx.x;
    for (int q = tid; q < 64 * 96; q += 256) {
        int r = q / 96, ci = q % 96;
        At[r][ci] = hpre[(size_t)(m0 + r) * 96 + ci];
    }
    for (int q = tid; q < 96 * 64; q += 256) {
        int jj = q / 96, i = q % 96;
        Bt[i][jj] = ipw[(size_t)(j0 + jj) * 96 + i];
    }
    __syncthreads();
    int row = tid >> 2, qq = tid & 3;
    float s = 0.f, s2 = 0.f;
    for (int ci = qq; ci < 96; ci += 4) { float v = At[row][ci]; s += v; s2 += v * v; }
    s += __shfl_xor(s, 1);  s += __shfl_xor(s, 2);
    s2 += __shfl_xor(s2, 1); s2 += __shfl_xor(s2, 2);
    float mean = s * (1.f / 96.f);
    float var = s2 * (1.f / 96.f) - mean * mean;
    float rstd = rsqrtf(var + EPSF);
    for (int ci = qq; ci < 96; ci += 4) {
        float v = At[row][ci];
        At[row][ci] = (v - mean) * rstd * lnw[ci] + lnb[ci];
    }
    __syncthreads();
    int tm = tid & 15, tn = tid >> 4;
    float acc[4][4];
#pragma unroll
    for (int r = 0; r < 4; r++)
#pragma unroll
        for (int cx = 0; cx < 4; cx++) acc[r][cx] = 0.f;
    for (int kk = 0; kk < 96; kk++) {
        float a0 = At[tm * 4 + 0][kk], a1 = At[tm * 4 + 1][kk];
        float a2 = At[tm * 4 + 2][kk], a3 = At[tm * 4 + 3][kk];
        float b0 = Bt[kk][tn * 4 + 0], b1 = Bt[kk][tn * 4 + 1];
        float b2 = Bt[kk][tn * 4 + 2], b3 = Bt[kk][tn * 4 + 3];
        acc[0][0] = fmaf(a0, b0, acc[0][0]); acc[0][1] = fmaf(a0, b1, acc[0][1]);
        acc[0][2] = fmaf(a0, b2, acc[0][2]); acc[0][3] = fmaf(a0, b3, acc[0][3]);
        acc[1][0] = fmaf(a1, b0, acc[1][0]); acc[1][1] = fmaf(a1, b1, acc[1][1]);
        acc[1][2] = fmaf(a1, b2, acc[1][2]); acc[1][3] = fmaf(a1, b3, acc[1][3]);
        acc[2][0] = fmaf(a2, b0, acc[2][0]); acc[2][1] = fmaf(a2, b1, acc[2][1]);
        acc[2][2] = fmaf(a2, b2, acc[2][2]); acc[2][3] = fmaf(a2, b3, acc[2][3]);
        acc[3][0] = fmaf(a3, b0, acc[3][0]); acc[3][1] = fmaf(a3, b1, acc[3][1]);
        acc[3][2] = fmaf(a3, b2, acc[3][2]); acc[3][3] = fmaf(a3, b3, acc[3][3]);
    }
#pragma unroll
    for (int r = 0; r < 4; r++) {
        int m = m0 + tm * 4 + r;
#pragma unroll
        for (int cx = 0; cx < 4; cx++) {
            int j = j0 + tn * 4 + cx;
            if (j < 192) xi[(size_t)m * 192 + j] = acc[r][cx];
            else         z[(size_t)m * 192 + (j - 192)] = acc[r][cx];
        }
    }
}

// K3: depthwise 3x3 conv + bias + SiLU -> xc [B,L,D]
__global__ __launch_bounds__(256) void k_dwconv2(const float* __restrict__ xi,
                                                 const float* __restrict__ w,
                                                 const float* __restrict__ bias,
                                                 float* __restrict__ xc) {
    int idx = blockIdx.x * 256 + threadIdx.x;        // over B*L*D, d fastest
    int d = idx % D192;
    int rest = idx / D192;
    int l = rest & 4095, b = rest >> 12;
    int hi = l >> 6, wi = l & 63;
    float acc = bias[d];
#pragma unroll
    for (int kh = 0; kh < 3; kh++) {
        int hh = hi + kh - 1;
        if (hh < 0 || hh >= 64) continue;
#pragma unroll
        for (int kw = 0; kw < 3; kw++) {
            int wp = wi + kw - 1;
            if (wp < 0 || wp >= 64) continue;
            acc += xi[((size_t)(b << 12) + hh * 64 + wp) * D192 + d] * w[d * 9 + kh * 3 + kw];
        }
    }
    xc[(size_t)idx] = silu_(acc);
}

// K4: x_proj (dts/Bs/Cs) + dt_proj + softplus. One block = 64 pixels.
__global__ __launch_bounds__(256) void k_proj(const float* __restrict__ xc,
                                              const float* __restrict__ xpw,
                                              const float* __restrict__ dtw,
                                              const float* __restrict__ dtb,
                                              float* __restrict__ delta,
                                              float* __restrict__ Bsb,
                                              float* __restrict__ Csb) {
    __shared__ float xt[64][193];
    __shared__ float dts[4][64][6];
    int m0 = blockIdx.x * 64;
    int tid = threadIdx.x;
    for (int q = tid; q < 64 * 192; q += 256) {
        int p = q / 192, d = q % 192;
        xt[p][d] = xc[(size_t)(m0 + p) * 192 + d];
    }
    __syncthreads();
    for (int q = tid; q < 4 * 38 * 64; q += 256) {
        int p = q & 63, kc = q >> 6;
        int k = kc / 38, c = kc % 38;
        const float* wr = xpw + (size_t)(k * 38 + c) * 192;
        float s = 0.f;
#pragma unroll 8
        for (int d = 0; d < 192; d++) s = fmaf(xt[p][d], wr[d], s);
        int m = m0 + p, b = m >> 12, l = m & 4095;
        int lseq = lperm(k, l);
        int bk = (b << 2) | k;
        if (c < 6)       dts[k][p][c] = s;
        else if (c < 22) Bsb[((size_t)bk * L_ + lseq) * N16 + (c - 6)] = s;
        else             Csb[((size_t)bk * L_ + lseq) * N16 + (c - 22)] = s;
    }
    __syncthreads();
    for (int q = tid; q < 4 * 64 * 192; q += 256) {
        int d = q % 192;
        int rest = q / 192;
        int p = rest & 63, k = rest >> 6;
        int m = m0 + p, b = m >> 12, l = m & 4095;
        int lseq = lperm(k, l);
        const float* wr = dtw + (size_t)(k * 192 + d) * 6;
        float s = dtb[k * 192 + d];
#pragma unroll
        for (int r = 0; r < 6; r++) s = fmaf(dts[k][p][r], wr[r], s);
        delta[((size_t)((b << 2) | k) * L_ + lseq) * D192 + d] = softplus_(s);
    }
}

// K5a: segmented scan pass 1 — per-segment summaries (P = prod dA, H = local h)
// grid (bk=8, dg=12, seg=64), block 256 = 16 d x 16 n
__global__ __launch_bounds__(256) void k_scan1(const float* __restrict__ xc,
                                               const float* __restrict__ delta,
                                               const float* __restrict__ Bsb,
                                               const float* __restrict__ Alogs,
                                               float* __restrict__ segP,
                                               float* __restrict__ segH) {
    int bk = blockIdx.x, seg = blockIdx.z;
    int b = bk >> 2, k = bk & 3;
    int g = threadIdx.x >> 4, n = threadIdx.x & 15;
    int d = blockIdx.y * 16 + g;
    float a = -expf(Alogs[(size_t)(k * D192 + d) * N16 + n]);
    const float* xcb = xc + (size_t)(b << 12) * D192;
    const float* dp = delta + (size_t)bk * L_ * D192;
    const float* Bp = Bsb + (size_t)bk * L_ * N16;
    float h = 0.f, P = 1.f;
    int l0 = seg * SEGLEN;
#pragma unroll 4
    for (int t = 0; t < SEGLEN; t++) {
        int l = l0 + t;
        int lsp = lperm(k, l);
        float u = xcb[(size_t)lsp * D192 + d];
        float dl = dp[(size_t)l * D192 + d];
        float Bn = Bp[l * N16 + n];
        float dA = __expf(dl * a);
        P *= dA;
        h = fmaf(h, dA, dl * u * Bn);
    }
    size_t o = (((size_t)bk * NSEG + seg) * D192 + d) * N16 + n;
    segP[o] = P;
    segH[o] = h;
}

// K5b: carry propagation across segments. One thread per (bk,d,n) channel.
__global__ __launch_bounds__(256) void k_scan2(const float* __restrict__ segP,
                                               const float* __restrict__ segH,
                                               float* __restrict__ carry) {
    int idx = blockIdx.x * 256 + threadIdx.x;   // bk*3072 + d*16 + n
    int bk = idx / 3072;
    int dn = idx % 3072;
    float c = 0.f;
    for (int s = 0; s < NSEG; s++) {
        size_t o = ((size_t)bk * NSEG + s) * 3072 + dn;
        carry[o] = c;
        c = fmaf(c, segP[o], segH[o]);
    }
}

// K5c: segmented scan pass 3 — re-scan with carry-in, emit y
__global__ __launch_bounds__(256) void k_scan3(const float* __restrict__ xc,
                                               const float* __restrict__ delta,
                                               const float* __restrict__ Bsb,
                                               const float* __restrict__ Csb,
                                               const float* __restrict__ Alogs,
                                               const float* __restrict__ Ds,
                                               const float* __restrict__ carry,
                                               float* __restrict__ outy) {
    int bk = blockIdx.x, seg = blockIdx.z;
    int b = bk >> 2, k = bk & 3;
    int g = threadIdx.x >> 4, n = threadIdx.x & 15;
    int d = blockIdx.y * 16 + g;
    float a = -expf(Alogs[(size_t)(k * D192 + d) * N16 + n]);
    float Dv = Ds[k * D192 + d];
    const float* xcb = xc + (size_t)(b << 12) * D192;
    const float* dp = delta + (size_t)bk * L_ * D192;
    const float* Bp = Bsb + (size_t)bk * L_ * N16;
    const float* Cp = Csb + (size_t)bk * L_ * N16;
    float* Op = outy + (size_t)bk * L_ * D192;
    float h = carry[(((size_t)bk * NSEG + seg) * D192 + d) * N16 + n];
    int l0 = seg * SEGLEN;
#pragma unroll 4
    for (int t = 0; t < SEGLEN; t++) {
        int l = l0 + t;
        int lsp = lperm(k, l);
        float u = xcb[(size_t)lsp * D192 + d];
        float dl = dp[(size_t)l * D192 + d];
        float Bn = Bp[l * N16 + n];
        float Cn = Cp[l * N16 + n];
        float dA = __expf(dl * a);
        h = fmaf(h, dA, dl * u * Bn);
        float yp = h * Cn;
        yp += __shfl_xor(yp, 1);
        yp += __shfl_xor(yp, 2);
        yp += __shfl_xor(yp, 4);
        yp += __shfl_xor(yp, 8);
        if (n == 0) Op[(size_t)l * D192 + d] = fmaf(Dv, u, yp);
    }
}

// K6: combine 4 directions + LN(out_norm) + *silu(z) + out_proj + add hpre -> h2
__global__ __launch_bounds__(256) void k_combine(const float* __restrict__ outy,
                                                 const float* __restrict__ onw,
                                                 const float* __restrict__ onb,
                                                 const float* __restrict__ z,
                                                 const float* __restrict__ opw,
                                                 const float* __restrict__ hpre,
                                                 float* __restrict__ h2) {
    __shared__ float yb[64][193];
    int m0 = blockIdx.x * 64;
    int tid = threadIdx.x;
    int b = m0 >> 12;
    const float* oy = outy + (size_t)(b << 2) * L_ * D192;
    for (int q = tid; q < 64 * 192; q += 256) {
        int d = q % 192, p = q / 192;
        int l = (m0 & 4095) + p;
        int l1 = swap64(l);
        float v = oy[((size_t)0 * L_ + l) * D192 + d]
                + oy[((size_t)2 * L_ + (4095 - l)) * D192 + d]
                + oy[((size_t)1 * L_ + l1) * D192 + d]
                + oy[((size_t)3 * L_ + (4095 - l1)) * D192 + d];
        yb[p][d] = v;
    }
    __syncthreads();
    int row = tid >> 2, qq = tid & 3;
    float s = 0.f, s2 = 0.f;
    for (int ci = qq; ci < 192; ci += 4) { float v = yb[row][ci]; s += v; s2 += v * v; }
    s += __shfl_xor(s, 1);  s += __shfl_xor(s, 2);
    s2 += __shfl_xor(s2, 1); s2 += __shfl_xor(s2, 2);
    float mean = s * (1.f / 192.f);
    float var = s2 * (1.f / 192.f) - mean * mean;
    float rstd = rsqrtf(var + EPSF);
    int m = m0 + row;
    for (int ci = qq; ci < 192; ci += 4) {
        float v = (yb[row][ci] - mean) * rstd * onw[ci] + onb[ci];
        float zz = z[(size_t)m * 192 + ci];
        yb[row][ci] = v * silu_(zz);
    }
    __syncthreads();
    for (int q = tid; q < 64 * 96; q += 256) {
        int p = q & 63, c = q >> 6;
        const float* wr = opw + (size_t)c * 192;
        float s3 = 0.f;
#pragma unroll 8
        for (int d = 0; d < 192; d++) s3 = fmaf(yb[p][d], wr[d], s3);
        int mm = m0 + p, bb = mm >> 12, l = mm & 4095;
        h2[((size_t)(bb * 96 + c)) * L_ + l] = hpre[(size_t)mm * 96 + c] + s3;
    }
}

// K7a: instance-norm stats over HW per (b,c)
__global__ __launch_bounds__(256) void k_instats(const float* __restrict__ h2,
                                                 float* __restrict__ stats) {
    int bc = blockIdx.x;
    int tid = threadIdx.x;
    const float* p = h2 + (size_t)bc * L_;
    float s = 0.f, s2 = 0.f;
    for (int i = tid; i < L_; i += 256) { float v = p[i]; s += v; s2 += v * v; }
#pragma unroll
    for (int off = 1; off < 64; off <<= 1) { s += __shfl_xor(s, off); s2 += __shfl_xor(s2, off); }
    __shared__ float w1[4], w2[4];
    int wv = tid >> 6;
    if ((tid & 63) == 0) { w1[wv] = s; w2[wv] = s2; }
    __syncthreads();
    if (tid == 0) {
        s = w1[0] + w1[1] + w1[2] + w1[3];
        s2 = w2[0] + w2[1] + w2[2] + w2[3];
        float mean = s * (1.f / L_);
        float var = s2 * (1.f / L_) - mean * mean;
        stats[bc * 2] = mean;
        stats[bc * 2 + 1] = rsqrtf(var + EPSF);
    }
}

// K7b: final: instance-norm apply + LeakyReLU + skip*scale -> f32 out [B,C,H,W]
__global__ __launch_bounds__(256) void k_final(const float* __restrict__ h2,
                                               const float* __restrict__ stats,
                                               const float* __restrict__ inw,
                                               const float* __restrict__ inb,
                                               const float* __restrict__ x,
                                               const float* __restrict__ scale,
                                               float* __restrict__ out) {
    int idx = blockIdx.x * 256 + threadIdx.x;
    int bc = idx >> 12;
    int c = bc % 96;
    float mean = stats[bc * 2], rstd = stats[bc * 2 + 1];
    float v = (h2[idx] - mean) * rstd * inw[c] + inb[c];
    v = (v >= 0.f) ? v : 0.01f * v;
    v = fmaf(x[idx], scale[0], v);
    out[idx] = v;
}

extern "C" void kernel_launch(void* const* d_in, const int* in_sizes, int n_in,
                              void* d_out, int out_size, void* d_ws, size_t ws_size,
                              hipStream_t stream) {
    const float* x         = (const float*)d_in[0];
    const float* conv_w    = (const float*)d_in[1];
    const float* conv_b    = (const float*)d_in[2];
    const float* inorm_w   = (const float*)d_in[3];
    const float* inorm_b   = (const float*)d_in[4];
    const float* scale     = (const float*)d_in[5];
    const float* ln_w      = (const float*)d_in[6];
    const float* ln_b      = (const float*)d_in[7];
    const float* in_proj_w = (const float*)d_in[8];
    const float* conv2_w   = (const float*)d_in[9];
    const float* conv2_b   = (const float*)d_in[10];
    const float* x_proj_w  = (const float*)d_in[11];
    const float* dt_proj_w = (const float*)d_in[12];
    const float* dt_proj_b = (const float*)d_in[13];
    const float* A_logs    = (const float*)d_in[14];
    const float* Ds        = (const float*)d_in[15];
    const float* out_nw    = (const float*)d_in[16];
    const float* out_nb    = (const float*)d_in[17];
    const float* out_pw    = (const float*)d_in[18];

    float* ws = (float*)d_ws;
    float* hpre  = ws;                    // 786432
    float* xi    = hpre + 786432;         // 1572864
    float* z     = xi + 1572864;          // 1572864
    float* xc    = z + 1572864;           // 1572864
    float* delta = xc + 1572864;          // 6291456
    float* Bsb   = delta + 6291456;       // 524288
    float* Csb   = Bsb + 524288;          // 524288
    float* outy  = Csb + 524288;          // 6291456
    float* h2    = outy + 6291456;        // 786432
    float* stats = h2 + 786432;           // 384

    // aliases (lifetime-disjoint):
    float* segP  = outy;                  // 1572864 (outy unwritten until scan3)
    float* segH  = outy + 1572864;        // 1572864
    float* carry = xi;                    // 1572864 (xi dead after dwconv2)

    k_dwconv1<<<3072, 256, 0, stream>>>(x, conv_w, conv_b, hpre);
    k_ln_inproj<<<dim3(128, 6), 256, 0, stream>>>(hpre, ln_w, ln_b, in_proj_w, xi, z);
    k_dwconv2<<<6144, 256, 0, stream>>>(xi, conv2_w, conv2_b, xc);
    k_proj<<<128, 256, 0, stream>>>(xc, x_proj_w, dt_proj_w, dt_proj_b, delta, Bsb, Csb);
    k_scan1<<<dim3(8, 12, 64), 256, 0, stream>>>(xc, delta, Bsb, A_logs, segP, segH);
    k_scan2<<<96, 256, 0, stream>>>(segP, segH, carry);
    k_scan3<<<dim3(8, 12, 64), 256, 0, stream>>>(xc, delta, Bsb, Csb, A_logs, Ds,
                                                 carry, outy);
    k_combine<<<128, 256, 0, stream>>>(outy, out_nw, out_nb, z, out_pw, hpre, h2);
    k_instats<<<192, 256, 0, stream>>>(h2, stats);
    k_final<<<3072, 256, 0, stream>>>(h2, stats, inorm_w, inorm_b, x, scale,
                                      (float*)d_out);
}

// Round 4
// 348.353 us; speedup vs baseline: 6.5476x; 1.5689x over previous
//
#include <hip/hip_runtime.h>
#include <hip/hip_bf16.h>
#include <math.h>

#define L_ 4096
#define C96 96
#define D192 192
#define N16 16
#define EPSF 1e-5f
#define NSEG 64
#define SEGLEN 64

__device__ __forceinline__ int swap64(int v) { return ((v & 63) << 6) | (v >> 6); }
__device__ __forceinline__ float silu_(float x) { return x / (1.f + __expf(-x)); }
__device__ __forceinline__ float softplus_(float x) { return (x > 20.f) ? x : log1pf(__expf(x)); }
__device__ __forceinline__ int lperm(int k, int l) {
    return (k == 0) ? l : (k == 1) ? swap64(l) : (k == 2) ? (4095 - l) : swap64(4095 - l);
}

// K1: depthwise 3x3 conv on x [B,C,H,W] -> hpre [B, L, C] (pixel-major BHWC)
__global__ __launch_bounds__(256) void k_dwconv1(const float* __restrict__ x,
                                                 const float* __restrict__ w,
                                                 const float* __restrict__ bias,
                                                 float* __restrict__ hpre) {
    int idx = blockIdx.x * 256 + threadIdx.x;       // over B*C*H*W
    int wi = idx & 63, hi = (idx >> 6) & 63, bc = idx >> 12;
    int c = bc % C96, b = bc / C96;
    const float* xp = x + (size_t)bc * L_;
    float acc = bias[c];
#pragma unroll
    for (int kh = 0; kh < 3; kh++) {
        int hh = hi + kh - 1;
        if (hh < 0 || hh >= 64) continue;
#pragma unroll
        for (int kw = 0; kw < 3; kw++) {
            int wp = wi + kw - 1;
            if (wp < 0 || wp >= 64) continue;
            acc += xp[hh * 64 + wp] * w[c * 9 + kh * 3 + kw];
        }
    }
    hpre[((size_t)b * L_ + hi * 64 + wi) * C96 + c] = acc;
}

// K2: LN over C (ln_w/ln_b) then in_proj GEMM
__global__ __launch_bounds__(256) void k_ln_inproj(const float* __restrict__ hpre,
                                                   const float* __restrict__ lnw,
                                                   const float* __restrict__ lnb,
                                                   const float* __restrict__ ipw,
                                                   float* __restrict__ xi,
                                                   float* __restrict__ z) {
    __shared__ float At[64][97];
    __shared__ float Bt[96][65];
    int m0 = blockIdx.x * 64;
    int j0 = blockIdx.y * 64;
    int tid = threadIdx.x;
    for (int q = tid; q < 64 * 96; q += 256) {
        int r = q / 96, ci = q % 96;
        At[r][ci] = hpre[(size_t)(m0 + r) * 96 + ci];
    }
    for (int q = tid; q < 96 * 64; q += 256) {
        int jj = q / 96, i = q % 96;
        Bt[i][jj] = ipw[(size_t)(j0 + jj) * 96 + i];
    }
    __syncthreads();
    int row = tid >> 2, qq = tid & 3;
    float s = 0.f, s2 = 0.f;
    for (int ci = qq; ci < 96; ci += 4) { float v = At[row][ci]; s += v; s2 += v * v; }
    s += __shfl_xor(s, 1);  s += __shfl_xor(s, 2);
    s2 += __shfl_xor(s2, 1); s2 += __shfl_xor(s2, 2);
    float mean = s * (1.f / 96.f);
    float var = s2 * (1.f / 96.f) - mean * mean;
    float rstd = rsqrtf(var + EPSF);
    for (int ci = qq; ci < 96; ci += 4) {
        float v = At[row][ci];
        At[row][ci] = (v - mean) * rstd * lnw[ci] + lnb[ci];
    }
    __syncthreads();
    int tm = tid & 15, tn = tid >> 4;
    float acc[4][4];
#pragma unroll
    for (int r = 0; r < 4; r++)
#pragma unroll
        for (int cx = 0; cx < 4; cx++) acc[r][cx] = 0.f;
    for (int kk = 0; kk < 96; kk++) {
        float a0 = At[tm * 4 + 0][kk], a1 = At[tm * 4 + 1][kk];
        float a2 = At[tm * 4 + 2][kk], a3 = At[tm * 4 + 3][kk];
        float b0 = Bt[kk][tn * 4 + 0], b1 = Bt[kk][tn * 4 + 1];
        float b2 = Bt[kk][tn * 4 + 2], b3 = Bt[kk][tn * 4 + 3];
        acc[0][0] = fmaf(a0, b0, acc[0][0]); acc[0][1] = fmaf(a0, b1, acc[0][1]);
        acc[0][2] = fmaf(a0, b2, acc[0][2]); acc[0][3] = fmaf(a0, b3, acc[0][3]);
        acc[1][0] = fmaf(a1, b0, acc[1][0]); acc[1][1] = fmaf(a1, b1, acc[1][1]);
        acc[1][2] = fmaf(a1, b2, acc[1][2]); acc[1][3] = fmaf(a1, b3, acc[1][3]);
        acc[2][0] = fmaf(a2, b0, acc[2][0]); acc[2][1] = fmaf(a2, b1, acc[2][1]);
        acc[2][2] = fmaf(a2, b2, acc[2][2]); acc[2][3] = fmaf(a2, b3, acc[2][3]);
        acc[3][0] = fmaf(a3, b0, acc[3][0]); acc[3][1] = fmaf(a3, b1, acc[3][1]);
        acc[3][2] = fmaf(a3, b2, acc[3][2]); acc[3][3] = fmaf(a3, b3, acc[3][3]);
    }
#pragma unroll
    for (int r = 0; r < 4; r++) {
        int m = m0 + tm * 4 + r;
#pragma unroll
        for (int cx = 0; cx < 4; cx++) {
            int j = j0 + tn * 4 + cx;
            if (j < 192) xi[(size_t)m * 192 + j] = acc[r][cx];
            else         z[(size_t)m * 192 + (j - 192)] = acc[r][cx];
        }
    }
}

// K3: depthwise 3x3 conv + bias + SiLU -> xc [B,L,D]
__global__ __launch_bounds__(256) void k_dwconv2(const float* __restrict__ xi,
                                                 const float* __restrict__ w,
                                                 const float* __restrict__ bias,
                                                 float* __restrict__ xc) {
    int idx = blockIdx.x * 256 + threadIdx.x;        // over B*L*D, d fastest
    int d = idx % D192;
    int rest = idx / D192;
    int l = rest & 4095, b = rest >> 12;
    int hi = l >> 6, wi = l & 63;
    float acc = bias[d];
#pragma unroll
    for (int kh = 0; kh < 3; kh++) {
        int hh = hi + kh - 1;
        if (hh < 0 || hh >= 64) continue;
#pragma unroll
        for (int kw = 0; kw < 3; kw++) {
            int wp = wi + kw - 1;
            if (wp < 0 || wp >= 64) continue;
            acc += xi[((size_t)(b << 12) + hh * 64 + wp) * D192 + d] * w[d * 9 + kh * 3 + kw];
        }
    }
    xc[(size_t)idx] = silu_(acc);
}

// K4a: build fused proj weights. Wfull[896][192]: per k (224 rows): Bs(16), Cs(16),
// delta(192) where delta rows = dtw[k] @ xpw_dt[k]. biasFull[896] = dtb on delta rows.
__global__ __launch_bounds__(256) void k_prepw(const float* __restrict__ xpw,
                                               const float* __restrict__ dtw,
                                               const float* __restrict__ dtb,
                                               float* __restrict__ Wfull,
                                               float* __restrict__ biasFull) {
    int idx = blockIdx.x * 256 + threadIdx.x;
    if (idx >= 896 * 192) return;
    int j = idx / 192, i = idx - j * 192;
    int k = j / 224, c = j - k * 224;
    float v;
    if (c < 16) {
        v = xpw[(size_t)(k * 38 + 6 + c) * 192 + i];
    } else if (c < 32) {
        v = xpw[(size_t)(k * 38 + 22 + (c - 16)) * 192 + i];
    } else {
        int dd = c - 32;
        v = 0.f;
#pragma unroll
        for (int r = 0; r < 6; r++)
            v = fmaf(dtw[(size_t)(k * 192 + dd) * 6 + r],
                     xpw[(size_t)(k * 38 + r) * 192 + i], v);
    }
    Wfull[(size_t)j * 192 + i] = v;
    if (i == 0) biasFull[j] = (c >= 32) ? dtb[k * 192 + (c - 32)] : 0.f;
}

// K4b: fused proj GEMM: [8192 x 192] @ [192 x 896] -> Bs/Cs/delta (+bias+softplus).
// 128x128 tile, K-chunk 32, 8x8 per thread. grid (64, 7).
__global__ __launch_bounds__(256) void k_proj2(const float* __restrict__ xc,
                                               const float* __restrict__ Wfull,
                                               const float* __restrict__ biasFull,
                                               float* __restrict__ delta,
                                               float* __restrict__ Bsb,
                                               float* __restrict__ Csb) {
    __shared__ float sm[8448];              // A: [32][132] @0, B: [32][132] @4224; staging [64][132]
    float* sA = sm;
    float* sB = sm + 4224;
    int m0 = blockIdx.x * 128;
    int j0 = blockIdx.y * 128;
    int b = m0 >> 12;
    int tid = threadIdx.x;
    int tm = tid & 15, tn = tid >> 4;
    float acc[8][8];
#pragma unroll
    for (int r = 0; r < 8; r++)
#pragma unroll
        for (int c = 0; c < 8; c++) acc[r][c] = 0.f;

    for (int kc = 0; kc < 192; kc += 32) {
        __syncthreads();
        for (int q = tid; q < 128 * 32; q += 256) {
            int p = q >> 5, dk = q & 31;
            sA[dk * 132 + p] = xc[(size_t)(m0 + p) * 192 + kc + dk];
        }
        for (int q = tid; q < 128 * 32; q += 256) {
            int jj = q >> 5, kk = q & 31;
            sB[kk * 132 + jj] = Wfull[(size_t)(j0 + jj) * 192 + kc + kk];
        }
        __syncthreads();
#pragma unroll 4
        for (int kk = 0; kk < 32; kk++) {
            float4 a0 = *(const float4*)(sA + kk * 132 + tm * 8);
            float4 a1 = *(const float4*)(sA + kk * 132 + tm * 8 + 4);
            float4 b0 = *(const float4*)(sB + kk * 132 + tn * 8);
            float4 b1 = *(const float4*)(sB + kk * 132 + tn * 8 + 4);
            float ar[8] = {a0.x, a0.y, a0.z, a0.w, a1.x, a1.y, a1.z, a1.w};
            float br[8] = {b0.x, b0.y, b0.z, b0.w, b1.x, b1.y, b1.z, b1.w};
#pragma unroll
            for (int r = 0; r < 8; r++)
#pragma unroll
                for (int c = 0; c < 8; c++)
                    acc[r][c] = fmaf(ar[r], br[c], acc[r][c]);
        }
    }

    // staged, coalesced stores: two rounds of 64 pixels each
#pragma unroll
    for (int half = 0; half < 2; half++) {
        __syncthreads();
        if ((tm >> 3) == half) {
#pragma unroll
            for (int r = 0; r < 8; r++)
#pragma unroll
                for (int c = 0; c < 8; c++)
                    sm[((tm & 7) * 8 + r) * 132 + tn * 8 + c] = acc[r][c];
        }
        __syncthreads();
        for (int q = tid; q < 64 * 128; q += 256) {
            int pp = q >> 7, jj = q & 127;
            int p = half * 64 + pp;
            float v = sm[pp * 132 + jj] + biasFull[j0 + jj];
            int j = j0 + jj;
            int k = j / 224, c = j - k * 224;
            int l = (m0 & 4095) + p;
            int lseq = lperm(k, l);
            size_t rowL = (size_t)((b << 2) | k) * L_ + lseq;
            if (c >= 32)      delta[rowL * 192 + (c - 32)] = softplus_(v);
            else if (c < 16)  Bsb[rowL * 16 + c] = v;
            else              Csb[rowL * 16 + (c - 16)] = v;
        }
    }
}

// K5a: segmented scan pass 1 — per-segment summaries (P = prod dA, H = local h)
__global__ __launch_bounds__(256) void k_scan1(const float* __restrict__ xc,
                                               const float* __restrict__ delta,
                                               const float* __restrict__ Bsb,
                                               const float* __restrict__ Alogs,
                                               float* __restrict__ segP,
                                               float* __restrict__ segH) {
    int bk = blockIdx.x, seg = blockIdx.z;
    int b = bk >> 2, k = bk & 3;
    int g = threadIdx.x >> 4, n = threadIdx.x & 15;
    int d = blockIdx.y * 16 + g;
    float a = -expf(Alogs[(size_t)(k * D192 + d) * N16 + n]);
    const float* xcb = xc + (size_t)(b << 12) * D192;
    const float* dp = delta + (size_t)bk * L_ * D192;
    const float* Bp = Bsb + (size_t)bk * L_ * N16;
    float h = 0.f, P = 1.f;
    int l0 = seg * SEGLEN;
#pragma unroll 4
    for (int t = 0; t < SEGLEN; t++) {
        int l = l0 + t;
        int lsp = lperm(k, l);
        float u = xcb[(size_t)lsp * D192 + d];
        float dl = dp[(size_t)l * D192 + d];
        float Bn = Bp[l * N16 + n];
        float dA = __expf(dl * a);
        P *= dA;
        h = fmaf(h, dA, dl * u * Bn);
    }
    size_t o = (((size_t)bk * NSEG + seg) * D192 + d) * N16 + n;
    segP[o] = P;
    segH[o] = h;
}

// K5b: carry propagation across segments. One thread per (bk,d,n) channel.
__global__ __launch_bounds__(256) void k_scan2(const float* __restrict__ segP,
                                               const float* __restrict__ segH,
                                               float* __restrict__ carry) {
    int idx = blockIdx.x * 256 + threadIdx.x;   // bk*3072 + d*16 + n
    int bk = idx / 3072;
    int dn = idx % 3072;
    float c = 0.f;
    for (int s = 0; s < NSEG; s++) {
        size_t o = ((size_t)bk * NSEG + s) * 3072 + dn;
        carry[o] = c;
        c = fmaf(c, segP[o], segH[o]);
    }
}

// K5c: segmented scan pass 3 — re-scan with carry-in, emit y
__global__ __launch_bounds__(256) void k_scan3(const float* __restrict__ xc,
                                               const float* __restrict__ delta,
                                               const float* __restrict__ Bsb,
                                               const float* __restrict__ Csb,
                                               const float* __restrict__ Alogs,
                                               const float* __restrict__ Ds,
                                               const float* __restrict__ carry,
                                               float* __restrict__ outy) {
    int bk = blockIdx.x, seg = blockIdx.z;
    int b = bk >> 2, k = bk & 3;
    int g = threadIdx.x >> 4, n = threadIdx.x & 15;
    int d = blockIdx.y * 16 + g;
    float a = -expf(Alogs[(size_t)(k * D192 + d) * N16 + n]);
    float Dv = Ds[k * D192 + d];
    const float* xcb = xc + (size_t)(b << 12) * D192;
    const float* dp = delta + (size_t)bk * L_ * D192;
    const float* Bp = Bsb + (size_t)bk * L_ * N16;
    const float* Cp = Csb + (size_t)bk * L_ * N16;
    float* Op = outy + (size_t)bk * L_ * D192;
    float h = carry[(((size_t)bk * NSEG + seg) * D192 + d) * N16 + n];
    int l0 = seg * SEGLEN;
#pragma unroll 4
    for (int t = 0; t < SEGLEN; t++) {
        int l = l0 + t;
        int lsp = lperm(k, l);
        float u = xcb[(size_t)lsp * D192 + d];
        float dl = dp[(size_t)l * D192 + d];
        float Bn = Bp[l * N16 + n];
        float Cn = Cp[l * N16 + n];
        float dA = __expf(dl * a);
        h = fmaf(h, dA, dl * u * Bn);
        float yp = h * Cn;
        yp += __shfl_xor(yp, 1);
        yp += __shfl_xor(yp, 2);
        yp += __shfl_xor(yp, 4);
        yp += __shfl_xor(yp, 8);
        if (n == 0) Op[(size_t)l * D192 + d] = fmaf(Dv, u, yp);
    }
}

// K6a: combine 4 directions + LN(out_norm) + *silu(z) -> yg [8192][192]
__global__ __launch_bounds__(256) void k_combine2(const float* __restrict__ outy,
                                                  const float* __restrict__ onw,
                                                  const float* __restrict__ onb,
                                                  const float* __restrict__ z,
                                                  float* __restrict__ yg) {
    __shared__ float yb[32][193];
    int m0 = blockIdx.x * 32;
    int tid = threadIdx.x;
    int b = m0 >> 12;
    const float* oy = outy + (size_t)(b << 2) * L_ * D192;
    for (int q = tid; q < 32 * 192; q += 256) {
        int p = q / 192, d = q - p * 192;
        int l = (m0 & 4095) + p;
        int l1 = swap64(l);
        float v = oy[((size_t)0 * L_ + l) * D192 + d]
                + oy[((size_t)2 * L_ + (4095 - l)) * D192 + d]
                + oy[((size_t)1 * L_ + l1) * D192 + d]
                + oy[((size_t)3 * L_ + (4095 - l1)) * D192 + d];
        yb[p][d] = v;
    }
    __syncthreads();
    int row = tid >> 3, qq = tid & 7;
    float s = 0.f, s2 = 0.f;
    for (int ci = qq; ci < 192; ci += 8) { float v = yb[row][ci]; s += v; s2 += v * v; }
    s += __shfl_xor(s, 1);  s += __shfl_xor(s, 2);  s += __shfl_xor(s, 4);
    s2 += __shfl_xor(s2, 1); s2 += __shfl_xor(s2, 2); s2 += __shfl_xor(s2, 4);
    float mean = s * (1.f / 192.f);
    float var = s2 * (1.f / 192.f) - mean * mean;
    float rstd = rsqrtf(var + EPSF);
    int m = m0 + row;
    for (int ci = qq; ci < 192; ci += 8) {
        float v = (yb[row][ci] - mean) * rstd * onw[ci] + onb[ci];
        float zz = z[(size_t)m * 192 + ci];
        yg[(size_t)m * 192 + ci] = v * silu_(zz);
    }
}

// K6b: out_proj GEMM [8192,192]@[192,96] + hpre -> h2 [(b*96+c)][L]
__global__ __launch_bounds__(256) void k_outproj(const float* __restrict__ yg,
                                                 const float* __restrict__ opw,
                                                 const float* __restrict__ hpre,
                                                 float* __restrict__ h2) {
    __shared__ float sa[64 * 34];
    __shared__ float sw[64 * 97];
    __shared__ float sc[32 * 97];
    int m0 = blockIdx.x * 32;
    int b = m0 >> 12;
    int tid = threadIdx.x;
    int tm = tid & 15, tn = tid >> 4;
    float acc[2][6];
#pragma unroll
    for (int r = 0; r < 2; r++)
#pragma unroll
        for (int c = 0; c < 6; c++) acc[r][c] = 0.f;
    for (int kc = 0; kc < 192; kc += 64) {
        __syncthreads();
        for (int q = tid; q < 32 * 64; q += 256) {
            int p = q >> 6, kk = q & 63;
            sa[kk * 34 + p] = yg[(size_t)(m0 + p) * 192 + kc + kk];
        }
        for (int q = tid; q < 96 * 64; q += 256) {
            int j = q >> 6, kk = q & 63;
            sw[kk * 97 + j] = opw[(size_t)j * 192 + kc + kk];
        }
        __syncthreads();
#pragma unroll 4
        for (int kk = 0; kk < 64; kk++) {
            float a0 = sa[kk * 34 + tm * 2], a1 = sa[kk * 34 + tm * 2 + 1];
#pragma unroll
            for (int c = 0; c < 6; c++) {
                float w = sw[kk * 97 + tn * 6 + c];
                acc[0][c] = fmaf(a0, w, acc[0][c]);
                acc[1][c] = fmaf(a1, w, acc[1][c]);
            }
        }
    }
    __syncthreads();
#pragma unroll
    for (int r = 0; r < 2; r++)
#pragma unroll
        for (int c = 0; c < 6; c++)
            sc[(tm * 2 + r) * 97 + tn * 6 + c] = acc[r][c];
    __syncthreads();
    for (int q = tid; q < 32 * 96; q += 256) {
        int p = q & 31, j = q >> 5;
        int m = m0 + p;
        float v = sc[p * 97 + j] + hpre[(size_t)m * 96 + j];
        h2[((size_t)(b * 96 + j)) * L_ + (m & 4095)] = v;
    }
}

// K7a: instance-norm stats over HW per (b,c)
__global__ __launch_bounds__(256) void k_instats(const float* __restrict__ h2,
                                                 float* __restrict__ stats) {
    int bc = blockIdx.x;
    int tid = threadIdx.x;
    const float* p = h2 + (size_t)bc * L_;
    float s = 0.f, s2 = 0.f;
    for (int i = tid; i < L_; i += 256) { float v = p[i]; s += v; s2 += v * v; }
#pragma unroll
    for (int off = 1; off < 64; off <<= 1) { s += __shfl_xor(s, off); s2 += __shfl_xor(s2, off); }
    __shared__ float w1[4], w2[4];
    int wv = tid >> 6;
    if ((tid & 63) == 0) { w1[wv] = s; w2[wv] = s2; }
    __syncthreads();
    if (tid == 0) {
        s = w1[0] + w1[1] + w1[2] + w1[3];
        s2 = w2[0] + w2[1] + w2[2] + w2[3];
        float mean = s * (1.f / L_);
        float var = s2 * (1.f / L_) - mean * mean;
        stats[bc * 2] = mean;
        stats[bc * 2 + 1] = rsqrtf(var + EPSF);
    }
}

// K7b: final: instance-norm apply + LeakyReLU + skip*scale -> f32 out [B,C,H,W]
__global__ __launch_bounds__(256) void k_final(const float* __restrict__ h2,
                                               const float* __restrict__ stats,
                                               const float* __restrict__ inw,
                                               const float* __restrict__ inb,
                                               const float* __restrict__ x,
                                               const float* __restrict__ scale,
                                               float* __restrict__ out) {
    int idx = blockIdx.x * 256 + threadIdx.x;
    int bc = idx >> 12;
    int c = bc % 96;
    float mean = stats[bc * 2], rstd = stats[bc * 2 + 1];
    float v = (h2[idx] - mean) * rstd * inw[c] + inb[c];
    v = (v >= 0.f) ? v : 0.01f * v;
    v = fmaf(x[idx], scale[0], v);
    out[idx] = v;
}

extern "C" void kernel_launch(void* const* d_in, const int* in_sizes, int n_in,
                              void* d_out, int out_size, void* d_ws, size_t ws_size,
                              hipStream_t stream) {
    const float* x         = (const float*)d_in[0];
    const float* conv_w    = (const float*)d_in[1];
    const float* conv_b    = (const float*)d_in[2];
    const float* inorm_w   = (const float*)d_in[3];
    const float* inorm_b   = (const float*)d_in[4];
    const float* scale     = (const float*)d_in[5];
    const float* ln_w      = (const float*)d_in[6];
    const float* ln_b      = (const float*)d_in[7];
    const float* in_proj_w = (const float*)d_in[8];
    const float* conv2_w   = (const float*)d_in[9];
    const float* conv2_b   = (const float*)d_in[10];
    const float* x_proj_w  = (const float*)d_in[11];
    const float* dt_proj_w = (const float*)d_in[12];
    const float* dt_proj_b = (const float*)d_in[13];
    const float* A_logs    = (const float*)d_in[14];
    const float* Ds        = (const float*)d_in[15];
    const float* out_nw    = (const float*)d_in[16];
    const float* out_nb    = (const float*)d_in[17];
    const float* out_pw    = (const float*)d_in[18];

    float* ws = (float*)d_ws;
    float* hpre  = ws;                    // 786432
    float* xi    = hpre + 786432;         // 1572864
    float* z     = xi + 1572864;          // 1572864
    float* xc    = z + 1572864;           // 1572864
    float* delta = xc + 1572864;          // 6291456
    float* Bsb   = delta + 6291456;       // 524288
    float* Csb   = Bsb + 524288;          // 524288
    float* outy  = Csb + 524288;          // 6291456
    float* h2    = outy + 6291456;        // 786432
    float* stats = h2 + 786432;           // 384

    // lifetime-disjoint aliases:
    float* segP  = outy;                  // scan summaries (outy unwritten until scan3)
    float* segH  = outy + 1572864;
    float* carry = xi;                    // xi dead after dwconv2 (until combine2)
    float* Wfull = outy + 4194304;        // 172032 floats, dead after k_proj2
    float* biasF = Wfull + 172032;        // 896
    float* yg    = xi;                    // combine2 output (carry dead after scan3)

    k_dwconv1<<<3072, 256, 0, stream>>>(x, conv_w, conv_b, hpre);
    k_prepw<<<672, 256, 0, stream>>>(x_proj_w, dt_proj_w, dt_proj_b, Wfull, biasF);
    k_ln_inproj<<<dim3(128, 6), 256, 0, stream>>>(hpre, ln_w, ln_b, in_proj_w, xi, z);
    k_dwconv2<<<6144, 256, 0, stream>>>(xi, conv2_w, conv2_b, xc);
    k_proj2<<<dim3(64, 7), 256, 0, stream>>>(xc, Wfull, biasF, delta, Bsb, Csb);
    k_scan1<<<dim3(8, 12, 64), 256, 0, stream>>>(xc, delta, Bsb, A_logs, segP, segH);
    k_scan2<<<96, 256, 0, stream>>>(segP, segH, carry);
    k_scan3<<<dim3(8, 12, 64), 256, 0, stream>>>(xc, delta, Bsb, Csb, A_logs, Ds,
                                                 carry, outy);
    k_combine2<<<256, 256, 0, stream>>>(outy, out_nw, out_nb, z, yg);
    k_outproj<<<256, 256, 0, stream>>>(yg, out_pw, hpre, h2);
    k_instats<<<192, 256, 0, stream>>>(h2, stats);
    k_final<<<3072, 256, 0, stream>>>(h2, stats, inorm_w, inorm_b, x, scale,
                                      (float*)d_out);
}

// Round 5
// 287.933 us; speedup vs baseline: 7.9216x; 1.2098x over previous
//
#include <hip/hip_runtime.h>
#include <hip/hip_bf16.h>
#include <math.h>

#define L_ 4096
#define C96 96
#define D192 192
#define N16 16
#define EPSF 1e-5f
#define NSEG 128
#define SEGLEN 32

__device__ __forceinline__ int swap64(int v) { return ((v & 63) << 6) | (v >> 6); }
__device__ __forceinline__ float silu_(float x) { return x / (1.f + __expf(-x)); }
__device__ __forceinline__ float softplus_(float x) { return (x > 20.f) ? x : log1pf(__expf(x)); }
__device__ __forceinline__ int lperm(int k, int l) {
    return (k == 0) ? l : (k == 1) ? swap64(l) : (k == 2) ? (4095 - l) : swap64(4095 - l);
}

// K1: depthwise 3x3 conv on x [B,C,H,W] -> hpre [B, L, C] (pixel-major BHWC)
__global__ __launch_bounds__(256) void k_dwconv1(const float* __restrict__ x,
                                                 const float* __restrict__ w,
                                                 const float* __restrict__ bias,
                                                 float* __restrict__ hpre) {
    int idx = blockIdx.x * 256 + threadIdx.x;       // over B*C*H*W
    int wi = idx & 63, hi = (idx >> 6) & 63, bc = idx >> 12;
    int c = bc % C96, b = bc / C96;
    const float* xp = x + (size_t)bc * L_;
    float acc = bias[c];
#pragma unroll
    for (int kh = 0; kh < 3; kh++) {
        int hh = hi + kh - 1;
        if (hh < 0 || hh >= 64) continue;
#pragma unroll
        for (int kw = 0; kw < 3; kw++) {
            int wp = wi + kw - 1;
            if (wp < 0 || wp >= 64) continue;
            acc += xp[hh * 64 + wp] * w[c * 9 + kh * 3 + kw];
        }
    }
    hpre[((size_t)b * L_ + hi * 64 + wi) * C96 + c] = acc;
}

// K2: LN over C (ln_w/ln_b) then in_proj GEMM
__global__ __launch_bounds__(256) void k_ln_inproj(const float* __restrict__ hpre,
                                                   const float* __restrict__ lnw,
                                                   const float* __restrict__ lnb,
                                                   const float* __restrict__ ipw,
                                                   float* __restrict__ xi,
                                                   float* __restrict__ z) {
    __shared__ float At[64][97];
    __shared__ float Bt[96][65];
    int m0 = blockIdx.x * 64;
    int j0 = blockIdx.y * 64;
    int tid = threadIdx.x;
    for (int q = tid; q < 64 * 96; q += 256) {
        int r = q / 96, ci = q % 96;
        At[r][ci] = hpre[(size_t)(m0 + r) * 96 + ci];
    }
    for (int q = tid; q < 96 * 64; q += 256) {
        int jj = q / 96, i = q % 96;
        Bt[i][jj] = ipw[(size_t)(j0 + jj) * 96 + i];
    }
    __syncthreads();
    int row = tid >> 2, qq = tid & 3;
    float s = 0.f, s2 = 0.f;
    for (int ci = qq; ci < 96; ci += 4) { float v = At[row][ci]; s += v; s2 += v * v; }
    s += __shfl_xor(s, 1);  s += __shfl_xor(s, 2);
    s2 += __shfl_xor(s2, 1); s2 += __shfl_xor(s2, 2);
    float mean = s * (1.f / 96.f);
    float var = s2 * (1.f / 96.f) - mean * mean;
    float rstd = rsqrtf(var + EPSF);
    for (int ci = qq; ci < 96; ci += 4) {
        float v = At[row][ci];
        At[row][ci] = (v - mean) * rstd * lnw[ci] + lnb[ci];
    }
    __syncthreads();
    int tm = tid & 15, tn = tid >> 4;
    float acc[4][4];
#pragma unroll
    for (int r = 0; r < 4; r++)
#pragma unroll
        for (int cx = 0; cx < 4; cx++) acc[r][cx] = 0.f;
    for (int kk = 0; kk < 96; kk++) {
        float a0 = At[tm * 4 + 0][kk], a1 = At[tm * 4 + 1][kk];
        float a2 = At[tm * 4 + 2][kk], a3 = At[tm * 4 + 3][kk];
        float b0 = Bt[kk][tn * 4 + 0], b1 = Bt[kk][tn * 4 + 1];
        float b2 = Bt[kk][tn * 4 + 2], b3 = Bt[kk][tn * 4 + 3];
        acc[0][0] = fmaf(a0, b0, acc[0][0]); acc[0][1] = fmaf(a0, b1, acc[0][1]);
        acc[0][2] = fmaf(a0, b2, acc[0][2]); acc[0][3] = fmaf(a0, b3, acc[0][3]);
        acc[1][0] = fmaf(a1, b0, acc[1][0]); acc[1][1] = fmaf(a1, b1, acc[1][1]);
        acc[1][2] = fmaf(a1, b2, acc[1][2]); acc[1][3] = fmaf(a1, b3, acc[1][3]);
        acc[2][0] = fmaf(a2, b0, acc[2][0]); acc[2][1] = fmaf(a2, b1, acc[2][1]);
        acc[2][2] = fmaf(a2, b2, acc[2][2]); acc[2][3] = fmaf(a2, b3, acc[2][3]);
        acc[3][0] = fmaf(a3, b0, acc[3][0]); acc[3][1] = fmaf(a3, b1, acc[3][1]);
        acc[3][2] = fmaf(a3, b2, acc[3][2]); acc[3][3] = fmaf(a3, b3, acc[3][3]);
    }
#pragma unroll
    for (int r = 0; r < 4; r++) {
        int m = m0 + tm * 4 + r;
#pragma unroll
        for (int cx = 0; cx < 4; cx++) {
            int j = j0 + tn * 4 + cx;
            if (j < 192) xi[(size_t)m * 192 + j] = acc[r][cx];
            else         z[(size_t)m * 192 + (j - 192)] = acc[r][cx];
        }
    }
}

// K3: depthwise 3x3 conv + bias + SiLU -> xc [B,L,D]
__global__ __launch_bounds__(256) void k_dwconv2(const float* __restrict__ xi,
                                                 const float* __restrict__ w,
                                                 const float* __restrict__ bias,
                                                 float* __restrict__ xc) {
    int idx = blockIdx.x * 256 + threadIdx.x;        // over B*L*D, d fastest
    int d = idx % D192;
    int rest = idx / D192;
    int l = rest & 4095, b = rest >> 12;
    int hi = l >> 6, wi = l & 63;
    float acc = bias[d];
#pragma unroll
    for (int kh = 0; kh < 3; kh++) {
        int hh = hi + kh - 1;
        if (hh < 0 || hh >= 64) continue;
#pragma unroll
        for (int kw = 0; kw < 3; kw++) {
            int wp = wi + kw - 1;
            if (wp < 0 || wp >= 64) continue;
            acc += xi[((size_t)(b << 12) + hh * 64 + wp) * D192 + d] * w[d * 9 + kh * 3 + kw];
        }
    }
    xc[(size_t)idx] = silu_(acc);
}

// K4a: build fused proj weights. Wfull[896][192]: per k (224 rows): Bs(16), Cs(16),
// delta(192) where delta rows = dtw[k] @ xpw_dt[k]. biasFull[896] = dtb on delta rows.
__global__ __launch_bounds__(256) void k_prepw(const float* __restrict__ xpw,
                                               const float* __restrict__ dtw,
                                               const float* __restrict__ dtb,
                                               float* __restrict__ Wfull,
                                               float* __restrict__ biasFull) {
    int idx = blockIdx.x * 256 + threadIdx.x;
    if (idx >= 896 * 192) return;
    int j = idx / 192, i = idx - j * 192;
    int k = j / 224, c = j - k * 224;
    float v;
    if (c < 16) {
        v = xpw[(size_t)(k * 38 + 6 + c) * 192 + i];
    } else if (c < 32) {
        v = xpw[(size_t)(k * 38 + 22 + (c - 16)) * 192 + i];
    } else {
        int dd = c - 32;
        v = 0.f;
#pragma unroll
        for (int r = 0; r < 6; r++)
            v = fmaf(dtw[(size_t)(k * 192 + dd) * 6 + r],
                     xpw[(size_t)(k * 38 + r) * 192 + i], v);
    }
    Wfull[(size_t)j * 192 + i] = v;
    if (i == 0) biasFull[j] = (c >= 32) ? dtb[k * 192 + (c - 32)] : 0.f;
}

// K4b: fused proj GEMM: [8192 x 192] @ [192 x 896] -> Bs/Cs/delta (+bias+softplus).
__global__ __launch_bounds__(256) void k_proj2(const float* __restrict__ xc,
                                               const float* __restrict__ Wfull,
                                               const float* __restrict__ biasFull,
                                               float* __restrict__ delta,
                                               float* __restrict__ Bsb,
                                               float* __restrict__ Csb) {
    __shared__ float sm[8448];              // A: [32][132] @0, B: [32][132] @4224
    float* sA = sm;
    float* sB = sm + 4224;
    int m0 = blockIdx.x * 128;
    int j0 = blockIdx.y * 128;
    int b = m0 >> 12;
    int tid = threadIdx.x;
    int tm = tid & 15, tn = tid >> 4;
    float acc[8][8];
#pragma unroll
    for (int r = 0; r < 8; r++)
#pragma unroll
        for (int c = 0; c < 8; c++) acc[r][c] = 0.f;

    for (int kc = 0; kc < 192; kc += 32) {
        __syncthreads();
        for (int q = tid; q < 128 * 32; q += 256) {
            int p = q >> 5, dk = q & 31;
            sA[dk * 132 + p] = xc[(size_t)(m0 + p) * 192 + kc + dk];
        }
        for (int q = tid; q < 128 * 32; q += 256) {
            int jj = q >> 5, kk = q & 31;
            sB[kk * 132 + jj] = Wfull[(size_t)(j0 + jj) * 192 + kc + kk];
        }
        __syncthreads();
#pragma unroll 4
        for (int kk = 0; kk < 32; kk++) {
            float4 a0 = *(const float4*)(sA + kk * 132 + tm * 8);
            float4 a1 = *(const float4*)(sA + kk * 132 + tm * 8 + 4);
            float4 b0 = *(const float4*)(sB + kk * 132 + tn * 8);
            float4 b1 = *(const float4*)(sB + kk * 132 + tn * 8 + 4);
            float ar[8] = {a0.x, a0.y, a0.z, a0.w, a1.x, a1.y, a1.z, a1.w};
            float br[8] = {b0.x, b0.y, b0.z, b0.w, b1.x, b1.y, b1.z, b1.w};
#pragma unroll
            for (int r = 0; r < 8; r++)
#pragma unroll
                for (int c = 0; c < 8; c++)
                    acc[r][c] = fmaf(ar[r], br[c], acc[r][c]);
        }
    }

#pragma unroll
    for (int half = 0; half < 2; half++) {
        __syncthreads();
        if ((tm >> 3) == half) {
#pragma unroll
            for (int r = 0; r < 8; r++)
#pragma unroll
                for (int c = 0; c < 8; c++)
                    sm[((tm & 7) * 8 + r) * 132 + tn * 8 + c] = acc[r][c];
        }
        __syncthreads();
        for (int q = tid; q < 64 * 128; q += 256) {
            int pp = q >> 7, jj = q & 127;
            int p = half * 64 + pp;
            float v = sm[pp * 132 + jj] + biasFull[j0 + jj];
            int j = j0 + jj;
            int k = j / 224, c = j - k * 224;
            int l = (m0 & 4095) + p;
            int lseq = lperm(k, l);
            size_t rowL = (size_t)((b << 2) | k) * L_ + lseq;
            if (c >= 32)      delta[rowL * 192 + (c - 32)] = softplus_(v);
            else if (c < 16)  Bsb[rowL * 16 + c] = v;
            else              Csb[rowL * 16 + (c - 16)] = v;
        }
    }
}

// K5a: scan pass 1 — thread per (bk,d), n in registers. grid (8, NSEG), block 192.
// Emits segP = exp(a*S), segH = local h.
__global__ __launch_bounds__(192) void k_scan1(const float* __restrict__ xc,
                                               const float* __restrict__ delta,
                                               const float* __restrict__ Bsb,
                                               const float* __restrict__ Alogs,
                                               float* __restrict__ segP,
                                               float* __restrict__ segH) {
    int bk = blockIdx.x, seg = blockIdx.y;
    int b = bk >> 2, k = bk & 3;
    int d = threadIdx.x;
    float a2[16];
#pragma unroll
    for (int n = 0; n < 16; n++)
        a2[n] = -expf(Alogs[(size_t)(k * D192 + d) * N16 + n]) * 1.4426950408889634f;
    int l0 = seg * SEGLEN;
    int lsp0 = lperm(k, l0);
    int dstep = (k == 0) ? 1 : (k == 1) ? 64 : (k == 2) ? -1 : -64;
    const float* up = xc + (size_t)(b << 12) * D192 + (size_t)lsp0 * D192 + d;
    const float* dp = delta + ((size_t)bk * L_ + l0) * D192 + d;
    const float* Bp = Bsb + ((size_t)bk * L_ + l0) * N16;
    long ustep = (long)dstep * D192;
    float h[16];
#pragma unroll
    for (int n = 0; n < 16; n++) h[n] = 0.f;
    float S = 0.f;
#pragma unroll 2
    for (int t = 0; t < SEGLEN; t++) {
        float u = *up;
        float dl = *dp;
        float x = dl * u;
        S += dl;
        float Bv[16];
#pragma unroll
        for (int n = 0; n < 16; n++) Bv[n] = Bp[n];
#pragma unroll
        for (int n = 0; n < 16; n++) {
            float dA = exp2f(dl * a2[n]);
            h[n] = fmaf(h[n], dA, x * Bv[n]);
        }
        up += ustep; dp += D192; Bp += N16;
    }
    size_t o = (((size_t)bk * NSEG + seg) * D192 + d) * N16;
#pragma unroll
    for (int n = 0; n < 16; n++) {
        segP[o + n] = exp2f(a2[n] * S);
        segH[o + n] = h[n];
    }
}

// K5b: carry propagation; writes carry IN PLACE over segP.
__global__ __launch_bounds__(64) void k_scan2(float* __restrict__ segP,
                                              const float* __restrict__ segH) {
    int idx = blockIdx.x * 64 + threadIdx.x;   // bk*3072 + dn  (24576 total)
    int bk = idx / 3072;
    int dn = idx % 3072;
    float c = 0.f;
    for (int s = 0; s < NSEG; s++) {
        size_t o = ((size_t)bk * NSEG + s) * 3072 + dn;
        float P = segP[o], H = segH[o];
        segP[o] = c;
        c = fmaf(c, P, H);
    }
}

// K5c: scan pass 3 — re-scan with carry, write y IN PLACE over delta.
__global__ __launch_bounds__(192) void k_scan3(const float* __restrict__ xc,
                                               float* __restrict__ delta,
                                               const float* __restrict__ Bsb,
                                               const float* __restrict__ Csb,
                                               const float* __restrict__ Alogs,
                                               const float* __restrict__ Ds,
                                               const float* __restrict__ carry) {
    int bk = blockIdx.x, seg = blockIdx.y;
    int b = bk >> 2, k = bk & 3;
    int d = threadIdx.x;
    float a2[16];
#pragma unroll
    for (int n = 0; n < 16; n++)
        a2[n] = -expf(Alogs[(size_t)(k * D192 + d) * N16 + n]) * 1.4426950408889634f;
    float Dv = Ds[k * D192 + d];
    int l0 = seg * SEGLEN;
    int lsp0 = lperm(k, l0);
    int dstep = (k == 0) ? 1 : (k == 1) ? 64 : (k == 2) ? -1 : -64;
    const float* up = xc + (size_t)(b << 12) * D192 + (size_t)lsp0 * D192 + d;
    float* dp = delta + ((size_t)bk * L_ + l0) * D192 + d;
    const float* Bp = Bsb + ((size_t)bk * L_ + l0) * N16;
    const float* Cp = Csb + ((size_t)bk * L_ + l0) * N16;
    long ustep = (long)dstep * D192;
    size_t o = (((size_t)bk * NSEG + seg) * D192 + d) * N16;
    float h[16];
#pragma unroll
    for (int n = 0; n < 16; n++) h[n] = carry[o + n];
#pragma unroll 2
    for (int t = 0; t < SEGLEN; t++) {
        float u = *up;
        float dl = *dp;
        float x = dl * u;
        float y = Dv * u;
        float Bv[16], Cv[16];
#pragma unroll
        for (int n = 0; n < 16; n++) Bv[n] = Bp[n];
#pragma unroll
        for (int n = 0; n < 16; n++) Cv[n] = Cp[n];
#pragma unroll
        for (int n = 0; n < 16; n++) {
            float dA = exp2f(dl * a2[n]);
            h[n] = fmaf(h[n], dA, x * Bv[n]);
            y = fmaf(h[n], Cv[n], y);
        }
        *dp = y;                       // in-place: y over delta
        up += ustep; dp += D192; Bp += N16; Cp += N16;
    }
}

// K6a: combine 4 directions + LN(out_norm) + *silu(z) -> yg [8192][192]
__global__ __launch_bounds__(256) void k_combine2(const float* __restrict__ outy,
                                                  const float* __restrict__ onw,
                                                  const float* __restrict__ onb,
                                                  const float* __restrict__ z,
                                                  float* __restrict__ yg) {
    __shared__ float yb[32][193];
    int m0 = blockIdx.x * 32;
    int tid = threadIdx.x;
    int b = m0 >> 12;
    const float* oy = outy + (size_t)(b << 2) * L_ * D192;
    for (int q = tid; q < 32 * 192; q += 256) {
        int p = q / 192, d = q - p * 192;
        int l = (m0 & 4095) + p;
        int l1 = swap64(l);
        float v = oy[((size_t)0 * L_ + l) * D192 + d]
                + oy[((size_t)2 * L_ + (4095 - l)) * D192 + d]
                + oy[((size_t)1 * L_ + l1) * D192 + d]
                + oy[((size_t)3 * L_ + (4095 - l1)) * D192 + d];
        yb[p][d] = v;
    }
    __syncthreads();
    int row = tid >> 3, qq = tid & 7;
    float s = 0.f, s2 = 0.f;
    for (int ci = qq; ci < 192; ci += 8) { float v = yb[row][ci]; s += v; s2 += v * v; }
    s += __shfl_xor(s, 1);  s += __shfl_xor(s, 2);  s += __shfl_xor(s, 4);
    s2 += __shfl_xor(s2, 1); s2 += __shfl_xor(s2, 2); s2 += __shfl_xor(s2, 4);
    float mean = s * (1.f / 192.f);
    float var = s2 * (1.f / 192.f) - mean * mean;
    float rstd = rsqrtf(var + EPSF);
    int m = m0 + row;
    for (int ci = qq; ci < 192; ci += 8) {
        float v = (yb[row][ci] - mean) * rstd * onw[ci] + onb[ci];
        float zz = z[(size_t)m * 192 + ci];
        yg[(size_t)m * 192 + ci] = v * silu_(zz);
    }
}

// K6b: out_proj GEMM [8192,192]@[192,96] + hpre -> h2 [(b*96+c)][L]
__global__ __launch_bounds__(256) void k_outproj(const float* __restrict__ yg,
                                                 const float* __restrict__ opw,
                                                 const float* __restrict__ hpre,
                                                 float* __restrict__ h2) {
    __shared__ float sa[64 * 34];
    __shared__ float sw[64 * 97];
    __shared__ float sc[32 * 97];
    int m0 = blockIdx.x * 32;
    int b = m0 >> 12;
    int tid = threadIdx.x;
    int tm = tid & 15, tn = tid >> 4;
    float acc[2][6];
#pragma unroll
    for (int r = 0; r < 2; r++)
#pragma unroll
        for (int c = 0; c < 6; c++) acc[r][c] = 0.f;
    for (int kc = 0; kc < 192; kc += 64) {
        __syncthreads();
        for (int q = tid; q < 32 * 64; q += 256) {
            int p = q >> 6, kk = q & 63;
            sa[kk * 34 + p] = yg[(size_t)(m0 + p) * 192 + kc + kk];
        }
        for (int q = tid; q < 96 * 64; q += 256) {
            int j = q >> 6, kk = q & 63;
            sw[kk * 97 + j] = opw[(size_t)j * 192 + kc + kk];
        }
        __syncthreads();
#pragma unroll 4
        for (int kk = 0; kk < 64; kk++) {
            float a0 = sa[kk * 34 + tm * 2], a1 = sa[kk * 34 + tm * 2 + 1];
#pragma unroll
            for (int c = 0; c < 6; c++) {
                float w = sw[kk * 97 + tn * 6 + c];
                acc[0][c] = fmaf(a0, w, acc[0][c]);
                acc[1][c] = fmaf(a1, w, acc[1][c]);
            }
        }
    }
    __syncthreads();
#pragma unroll
    for (int r = 0; r < 2; r++)
#pragma unroll
        for (int c = 0; c < 6; c++)
            sc[(tm * 2 + r) * 97 + tn * 6 + c] = acc[r][c];
    __syncthreads();
    for (int q = tid; q < 32 * 96; q += 256) {
        int p = q & 31, j = q >> 5;
        int m = m0 + p;
        float v = sc[p * 97 + j] + hpre[(size_t)m * 96 + j];
        h2[((size_t)(b * 96 + j)) * L_ + (m & 4095)] = v;
    }
}

// K7a: instance-norm stats over HW per (b,c)
__global__ __launch_bounds__(256) void k_instats(const float* __restrict__ h2,
                                                 float* __restrict__ stats) {
    int bc = blockIdx.x;
    int tid = threadIdx.x;
    const float* p = h2 + (size_t)bc * L_;
    float s = 0.f, s2 = 0.f;
    for (int i = tid; i < L_; i += 256) { float v = p[i]; s += v; s2 += v * v; }
#pragma unroll
    for (int off = 1; off < 64; off <<= 1) { s += __shfl_xor(s, off); s2 += __shfl_xor(s2, off); }
    __shared__ float w1[4], w2[4];
    int wv = tid >> 6;
    if ((tid & 63) == 0) { w1[wv] = s; w2[wv] = s2; }
    __syncthreads();
    if (tid == 0) {
        s = w1[0] + w1[1] + w1[2] + w1[3];
        s2 = w2[0] + w2[1] + w2[2] + w2[3];
        float mean = s * (1.f / L_);
        float var = s2 * (1.f / L_) - mean * mean;
        stats[bc * 2] = mean;
        stats[bc * 2 + 1] = rsqrtf(var + EPSF);
    }
}

// K7b: final: instance-norm apply + LeakyReLU + skip*scale -> f32 out [B,C,H,W]
__global__ __launch_bounds__(256) void k_final(const float* __restrict__ h2,
                                               const float* __restrict__ stats,
                                               const float* __restrict__ inw,
                                               const float* __restrict__ inb,
                                               const float* __restrict__ x,
                                               const float* __restrict__ scale,
                                               float* __restrict__ out) {
    int idx = blockIdx.x * 256 + threadIdx.x;
    int bc = idx >> 12;
    int c = bc % 96;
    float mean = stats[bc * 2], rstd = stats[bc * 2 + 1];
    float v = (h2[idx] - mean) * rstd * inw[c] + inb[c];
    v = (v >= 0.f) ? v : 0.01f * v;
    v = fmaf(x[idx], scale[0], v);
    out[idx] = v;
}

extern "C" void kernel_launch(void* const* d_in, const int* in_sizes, int n_in,
                              void* d_out, int out_size, void* d_ws, size_t ws_size,
                              hipStream_t stream) {
    const float* x         = (const float*)d_in[0];
    const float* conv_w    = (const float*)d_in[1];
    const float* conv_b    = (const float*)d_in[2];
    const float* inorm_w   = (const float*)d_in[3];
    const float* inorm_b   = (const float*)d_in[4];
    const float* scale     = (const float*)d_in[5];
    const float* ln_w      = (const float*)d_in[6];
    const float* ln_b      = (const float*)d_in[7];
    const float* in_proj_w = (const float*)d_in[8];
    const float* conv2_w   = (const float*)d_in[9];
    const float* conv2_b   = (const float*)d_in[10];
    const float* x_proj_w  = (const float*)d_in[11];
    const float* dt_proj_w = (const float*)d_in[12];
    const float* dt_proj_b = (const float*)d_in[13];
    const float* A_logs    = (const float*)d_in[14];
    const float* Ds        = (const float*)d_in[15];
    const float* out_nw    = (const float*)d_in[16];
    const float* out_nb    = (const float*)d_in[17];
    const float* out_pw    = (const float*)d_in[18];

    float* ws = (float*)d_ws;
    float* hpre  = ws;                    // 786432
    float* xi    = hpre + 786432;         // 1572864
    float* z     = xi + 1572864;          // 1572864
    float* xc    = z + 1572864;           // 1572864
    float* delta = xc + 1572864;          // 6291456 (y written in-place by scan3)
    float* Bsb   = delta + 6291456;       // 524288
    float* Csb   = Bsb + 524288;          // 524288
    float* outy  = Csb + 524288;          // 6291456 (holds segP|segH during scan)
    float* h2    = outy + 6291456;        // 786432
    float* stats = h2 + 786432;           // 384

    // lifetime-disjoint aliases:
    float* segP  = outy;                  // 3145728 = 8*128*192*16 ; carries in-place
    float* segH  = outy + 3145728;        // 3145728
    float* Wfull = outy + 4194304;        // inside segH region, dead before scan1
    float* biasF = Wfull + 172032;        // 896
    float* yg    = xi;                    // combine2 output (xi dead after dwconv2)

    k_dwconv1<<<3072, 256, 0, stream>>>(x, conv_w, conv_b, hpre);
    k_prepw<<<672, 256, 0, stream>>>(x_proj_w, dt_proj_w, dt_proj_b, Wfull, biasF);
    k_ln_inproj<<<dim3(128, 6), 256, 0, stream>>>(hpre, ln_w, ln_b, in_proj_w, xi, z);
    k_dwconv2<<<6144, 256, 0, stream>>>(xi, conv2_w, conv2_b, xc);
    k_proj2<<<dim3(64, 7), 256, 0, stream>>>(xc, Wfull, biasF, delta, Bsb, Csb);
    k_scan1<<<dim3(8, NSEG), 192, 0, stream>>>(xc, delta, Bsb, A_logs, segP, segH);
    k_scan2<<<384, 64, 0, stream>>>(segP, segH);
    k_scan3<<<dim3(8, NSEG), 192, 0, stream>>>(xc, delta, Bsb, Csb, A_logs, Ds, segP);
    k_combine2<<<256, 256, 0, stream>>>(delta, out_nw, out_nb, z, yg);
    k_outproj<<<256, 256, 0, stream>>>(yg, out_pw, hpre, h2);
    k_instats<<<192, 256, 0, stream>>>(h2, stats);
    k_final<<<3072, 256, 0, stream>>>(h2, stats, inorm_w, inorm_b, x, scale,
                                      (float*)d_out);
}